// Round 17
// baseline (51.416 us; speedup 1.0000x reference)
//
#include <hip/hip_runtime.h>
#include <math.h>

#define INDIM 10
#define DIM 32
#define LAYERS 4
#define MODES 17

#define LOG2E 1.4426950408889634f
#define LN2   0.6931471805599453f

// d_ws layout:
//   [0, 11264)        : frag f16 [11][64][8]  (16x16 A-operand fragments)
//   [11264, 12032)    : bias2 f32 [6][32]     (compact per-stage bias tables)
#define WS_FRAG_OFF 0
#define WS_BIAS_OFF 11264

typedef _Float16 f16;
typedef _Float16 f16x8 __attribute__((ext_vector_type(8)));
typedef float f32x4v __attribute__((ext_vector_type(4)));
typedef unsigned u32x2 __attribute__((ext_vector_type(2)));

union BU { f16x8 v; unsigned u[4]; };

// ---------------------------------------------------------------------------
// FUSED 2-phase prep (R16-verified speed), retargeted at 16x16 fragments.
// 16x16x32 layouts (R3/R4-verified): A row=lane&15, k=8*(lane>>4)+e;
// B col=lane&15, k=8*(lane>>4)+e; D col=lane&15, row=4*(lane>>4)+reg.
// Layer frag f=2l+h holds A_h = W^T rows 16h..16h+15 (output feats), k=input.
// f=8,9: stem halves; f=10: head (outdim 10 -> single frag, LN2-folded).
// log2e folding verified R11: Wc[0]*=LOG2E, projB*=LOG2E, headW*=LN2.
// ---------------------------------------------------------------------------
__global__ void fno_prep(const float* __restrict__ wr,
                         const float* __restrict__ wi,
                         const float* __restrict__ projW,
                         const float* __restrict__ stemW,
                         const float* __restrict__ headW,
                         const float* __restrict__ stemB,
                         const float* __restrict__ projB,
                         const float* __restrict__ headB,
                         f16* __restrict__ frag,
                         float* __restrict__ bias2) {
    const int l  = blockIdx.x;
    const int tx = threadIdx.x;
    const int j  = tx & 31;   // output feat
    const int n  = tx >> 5;   // input feat (k)

    __shared__ float ct[32], st[32];
    __shared__ float sre[MODES][32], sim[MODES][32];
    if (tx < 32) {
        float ang = (2.0f * 3.14159265358979323846f / 32.0f) * (float)tx;
        ct[tx] = cosf(ang);
        st[tx] = sinf(ang);
    }
    __syncthreads();

    const float* lwr = wr + l * MODES * MODES;
    const float* lwi = wi + l * MODES * MODES;

    // phase 1: y_o(n) once per (o,n)
    if (tx < MODES * 32) {
        const int o  = tx >> 5;
        const int nn = tx & 31;
        float re = 0.0f, im = 0.0f;
        for (int m = 0; m < MODES; ++m) {
            int t = (m * nn) & 31;
            float c = ct[t], s = st[t];
            float a = lwr[m * MODES + o];
            float b = lwi[m * MODES + o];
            re += c * a + s * b;
            im += c * b - s * a;
        }
        sre[o][nn] = re;
        sim[o][nn] = im;
    }
    __syncthreads();

    // phase 2: o-sum from LDS broadcast
    float acc = 0.0f;
    for (int o = 0; o < MODES; ++o) {
        int t2 = (o * j) & 31;
        float f = (o == 0 || o == 16) ? 1.0f : 2.0f;
        acc += f * (sre[o][n] * ct[t2] - sim[o][n] * st[t2]);
    }
    acc = acc * (1.0f / 32.0f) + projW[(l * DIM + n) * DIM + j];

    const float wscale = (l == 0) ? LOG2E : 1.0f;
    // 16x16 A-frag mapping: f=2l+(j>>4), lane=16*(n>>3)+(j&15), e=n&7
    const int h  = j >> 4;
    const int ln = 16 * (n >> 3) + (j & 15);
    const int e  = n & 7;
    frag[((l * 2 + h) * 64 + ln) * 8 + e] = (f16)(wscale * acc);

    if (l == 0) {
        if (tx < 64) {
            const int lnn = tx;
            const int c2  = lnn & 15;
            const int g2  = lnn >> 4;
#pragma unroll
            for (int hh = 0; hh < 2; ++hh)
#pragma unroll
                for (int ee = 0; ee < 8; ++ee) {
                    int k = 8 * g2 + ee;
                    frag[((8 + hh) * 64 + lnn) * 8 + ee] =
                        (f16)(k < INDIM ? stemW[k * DIM + 16 * hh + c2] : 0.0f);
                }
#pragma unroll
            for (int ee = 0; ee < 8; ++ee) {
                int k = 8 * g2 + ee;
                frag[(10 * 64 + lnn) * 8 + ee] =
                    (f16)(c2 < INDIM ? LN2 * headW[k * INDIM + c2] : 0.0f);
            }
        }
        if (tx < 32) {
#pragma unroll
            for (int f = 0; f < 6; ++f) {
                float v;
                if (f == 0)      v = stemB[tx];
                else if (f <= 4) v = LOG2E * projB[(f - 1) * DIM + tx];
                else             v = (tx < INDIM) ? headB[tx] : 0.0f;
                bias2[f * 32 + tx] = v;
            }
        }
    }
}

__device__ __forceinline__ float exp2_fast(float x) {
#if __has_builtin(__builtin_amdgcn_exp2f)
    return __builtin_amdgcn_exp2f(x);
#else
    return exp2f(x);
#endif
}

__device__ __forceinline__ unsigned pk2(float a, float b) {
    auto h2 = __builtin_amdgcn_cvt_pkrtz(a, b);
    return __builtin_bit_cast(unsigned, h2);
}

// lane<32 <-> lane>=32 exchange (R8-verified builtin path).
__device__ __forceinline__ void pswap32(unsigned& a, unsigned& b) {
#if __has_builtin(__builtin_amdgcn_permlane32_swap)
    u32x2 r = __builtin_amdgcn_permlane32_swap(a, b, false, false);
    a = r[0];
    b = r[1];
#else
    asm("v_permlane32_swap_b32 %0, %1" : "+v"(a), "+v"(b));
    __builtin_amdgcn_sched_barrier(0);
#endif
}

// lane<->lane^16 exchange within each 32-half (gfx950 v_permlane16_swap_b32):
// lanes bit4==0: a'=own a, b'=a(lane+16); lanes bit4==1: a'=b(lane-16), b'=own b.
__device__ __forceinline__ void pswap16(unsigned& a, unsigned& b) {
#if __has_builtin(__builtin_amdgcn_permlane16_swap)
    u32x2 r = __builtin_amdgcn_permlane16_swap(a, b, false, false);
    a = r[0];
    b = r[1];
#else
    asm("v_permlane16_swap_b32 %0, %1" : "+v"(a), "+v"(b));
    __builtin_amdgcn_sched_barrier(0);
#endif
}

// D0,D1 (two 16x16 f32x4 halves: lane has feats 4g..4g+3 of half h) ->
// next-layer B-frag (lane needs feats 8g..8g+7 as f16).  Derivation
// (symbolic, all 4 lane-groups checked):
//   P=pk2(D0 pairs), Q=pk2(D1 pairs); swap32(P[d],Q[d]); swap16(P[d],Q[d]);
//   frag = [P0,P1,Q0,Q1].
template <bool SILU>
__device__ __forceinline__ void pack_exchange16(const f32x4v& D0, const f32x4v& D1,
                                                BU& b) {
    float s[8];
    if (SILU) {
        float u[8];
#pragma unroll
        for (int r = 0; r < 4; ++r) { u[r] = exp2_fast(-D0[r]); u[4 + r] = exp2_fast(-D1[r]); }
#pragma unroll
        for (int r = 0; r < 8; ++r) u[r] = 1.0f + u[r];
#pragma unroll
        for (int r = 0; r < 8; ++r) u[r] = __builtin_amdgcn_rcpf(u[r]);
#pragma unroll
        for (int r = 0; r < 4; ++r) { s[r] = D0[r] * u[r]; s[4 + r] = D1[r] * u[4 + r]; }
    } else {
#pragma unroll
        for (int r = 0; r < 4; ++r) { s[r] = D0[r]; s[4 + r] = D1[r]; }
    }
    unsigned P0 = pk2(s[0], s[1]);
    unsigned P1 = pk2(s[2], s[3]);
    unsigned Q0 = pk2(s[4], s[5]);
    unsigned Q1 = pk2(s[6], s[7]);
    pswap32(P0, Q0);
    pswap32(P1, Q1);
    pswap16(P0, Q0);
    pswap16(P1, Q1);
    b.u[0] = P0; b.u[1] = P1; b.u[2] = Q0; b.u[3] = Q1;
}

// Bias C-operand (f32x4) for feat-half h: bias[stage][16h + 4g + r].
__device__ __forceinline__ f32x4v ld_bias4(const float* sbias, int stage, int h, int g) {
    float4 q = *(const float4*)&sbias[stage * 32 + 16 * h + 4 * g];
    f32x4v v = {q.x, q.y, q.z, q.w};
    return v;
}

__device__ __forceinline__ f16x8 ld_frag(const f16* sfrag, int f, int ln) {
    return *(const f16x8*)&sfrag[(f * 64 + ln) * 8];
}

// x -> B-frag: col=lane&15 = batch row, k=8g+e = input feat (zeros for k>=10).
template <bool GUARD>
__device__ __forceinline__ BU load_x(const float* __restrict__ x, long rb,
                                     int c, int g, int nrows) {
    BU b;
    b.u[0] = 0; b.u[1] = 0; b.u[2] = 0; b.u[3] = 0;
    const long r = rb + c;
    if (!GUARD || r < nrows) {
        const float* xp = x + r * INDIM;
        if (g == 0) {
            float2 p0 = *(const float2*)(xp + 0);
            float2 p1 = *(const float2*)(xp + 2);
            float2 p2 = *(const float2*)(xp + 4);
            float2 p3 = *(const float2*)(xp + 6);
            b.u[0] = pk2(p0.x, p0.y);
            b.u[1] = pk2(p1.x, p1.y);
            b.u[2] = pk2(p2.x, p2.y);
            b.u[3] = pk2(p3.x, p3.y);
        } else if (g == 1) {
            float2 p4 = *(const float2*)(xp + 8);
            b.u[0] = pk2(p4.x, p4.y);
        }
    }
    return b;
}

// Head D (16x16): lane = batch c, out-feats 4g+r (g3 idle, g2 only f8,f9).
template <bool GUARD>
__device__ __forceinline__ void store_o(float* __restrict__ out, long rb,
                                        int c, int g, int nrows, const f32x4v& H) {
    const long r = rb + c;
    if (!GUARD || r < nrows) {
        float* op = out + r * INDIM;
        if (g == 0) {
            *(float2*)(op + 0) = make_float2(H[0], H[1]);
            *(float2*)(op + 2) = make_float2(H[2], H[3]);
        } else if (g == 1) {
            *(float2*)(op + 4) = make_float2(H[0], H[1]);
            *(float2*)(op + 6) = make_float2(H[2], H[3]);
        } else if (g == 2) {
            *(float2*)(op + 8) = make_float2(H[0], H[1]);
        }
    }
}

// ---------------------------------------------------------------------------
// Main: 16x16x32 MFMA pipeline, one 16-row tile per wave.  Halved per-wave
// state vs the 32x32 version (2x f32x4 acc, one 4-dword B-frag) -> the
// 64-combined-reg class -> 8 waves/SIMD.  R15 proved delivered waves
// convert to speed; R16 proved 32x32 state can't shrink -- this shrinks it
// algorithmically.  Weights in LDS (R14), bias at-use (R13), stage-major
// silu (R11), log2e fold (R11), 2-phase prep (R16).
// ---------------------------------------------------------------------------
template <bool GUARD>
__global__ __launch_bounds__(256, 8) void fno_main(
    const float* __restrict__ x,
    const f16*  __restrict__ fragbuf,   // [11][64][8] f16
    const float* __restrict__ bias2,    // [6][32] f32
    float* __restrict__ out,
    int nrows) {

    __shared__ __align__(16) f16 sfrag[11 * 64 * 8];   // 11264 B
    __shared__ __align__(16) float sbias[6 * 32];      // 768 B

    {
        const int tid = threadIdx.x;
        uint4* dv = (uint4*)sfrag;
        const uint4* sv = (const uint4*)fragbuf;
#pragma unroll
        for (int i = 0; i < 3; ++i) {
            int idx = tid + i * 256;
            if (idx < 704) dv[idx] = sv[idx];
        }
        if (tid < 48) ((float4*)sbias)[tid] = ((const float4*)bias2)[tid];
    }
    __syncthreads();

    const int tid = threadIdx.x;
    const int w   = tid >> 6;
    const int ln  = tid & 63;
    const int c   = ln & 15;   // batch col
    const int g   = ln >> 4;   // k-group / D-row group

    const long rb = (long)blockIdx.x * 64 + (long)w * 16;

    // ---- stem: 2 MFMAs (feat halves), K=32 covers indim ----
    BU bx = load_x<GUARD>(x, rb, c, g, nrows);
    f16x8 as0 = ld_frag(sfrag, 8, ln);
    f16x8 as1 = ld_frag(sfrag, 9, ln);
    f32x4v D0 = __builtin_amdgcn_mfma_f32_16x16x32_f16(as0, bx.v, ld_bias4(sbias, 0, 0, g), 0, 0, 0);
    f32x4v D1 = __builtin_amdgcn_mfma_f32_16x16x32_f16(as1, bx.v, ld_bias4(sbias, 0, 1, g), 0, 0, 0);

    BU b;
    pack_exchange16<false>(D0, D1, b);

    // ---- 4 fused layers: 2 MFMAs each, reg-only exchange between ----
#pragma unroll
    for (int l = 0; l < LAYERS; ++l) {
        f16x8 w0 = ld_frag(sfrag, 2 * l, ln);
        f16x8 w1 = ld_frag(sfrag, 2 * l + 1, ln);
        f32x4v t0 = __builtin_amdgcn_mfma_f32_16x16x32_f16(w0, b.v, ld_bias4(sbias, 1 + l, 0, g), 0, 0, 0);
        f32x4v t1 = __builtin_amdgcn_mfma_f32_16x16x32_f16(w1, b.v, ld_bias4(sbias, 1 + l, 1, g), 0, 0, 0);
        pack_exchange16<true>(t0, t1, b);
    }

    // ---- head: ONE MFMA (outdim 10 <= 16) ----
    f16x8 ah = ld_frag(sfrag, 10, ln);
    f32x4v H = __builtin_amdgcn_mfma_f32_16x16x32_f16(ah, b.v, ld_bias4(sbias, 5, 0, g), 0, 0, 0);

    store_o<GUARD>(out, rb, c, g, nrows, H);
}

extern "C" void kernel_launch(void* const* d_in, const int* in_sizes, int n_in,
                              void* d_out, int out_size, void* d_ws, size_t ws_size,
                              hipStream_t stream) {
    const float* x      = (const float*)d_in[0];
    const float* stemW  = (const float*)d_in[1];
    const float* stemB  = (const float*)d_in[2];
    const float* fno_wr = (const float*)d_in[3];
    const float* fno_wi = (const float*)d_in[4];
    const float* projW  = (const float*)d_in[5];
    const float* projB  = (const float*)d_in[6];
    const float* headW  = (const float*)d_in[7];
    const float* headB  = (const float*)d_in[8];
    float* out = (float*)d_out;

    f16*   frag  = (f16*)((char*)d_ws + WS_FRAG_OFF);
    float* bias2 = (float*)((char*)d_ws + WS_BIAS_OFF);

    const int nrows = in_sizes[0] / INDIM;

    fno_prep<<<LAYERS, 1024, 0, stream>>>(fno_wr, fno_wi, projW, stemW, headW,
                                          stemB, projB, headB, frag, bias2);

    const int rows_per_block = 64;   // 4 waves x 16 rows
    const int nblk = (nrows + rows_per_block - 1) / rows_per_block;
    if (nrows % rows_per_block == 0)
        fno_main<false><<<nblk, 256, 0, stream>>>(x, frag, bias2, out, nrows);
    else
        fno_main<true><<<nblk, 256, 0, stream>>>(x, frag, bias2, out, nrows);
}